// Round 11
// baseline (294.455 us; speedup 1.0000x reference)
//
#include <hip/hip_runtime.h>

#define NN 8192
#define EE 131072
#define HH 128
#define NEGV -1.0e30f
#define SEG 128
#define NSEG (NN / SEG)   // 64
#define VT 128            // v-rows per stage1 block (8 waves x 16)

typedef __attribute__((ext_vector_type(8))) short bf16x8;
typedef __attribute__((ext_vector_type(4))) float f32x4;

typedef __attribute__((address_space(1))) unsigned int AS1U;
typedef __attribute__((address_space(3))) unsigned int AS3U;

__device__ __forceinline__ unsigned short f2bf(float f) {
    unsigned int u = __float_as_uint(f);
    unsigned int r = u + 0x7fffu + ((u >> 16) & 1u);
    return (unsigned short)(r >> 16);
}
__device__ __forceinline__ float bf2f(unsigned short b) {
    return __uint_as_float((unsigned int)b << 16);
}

// ---------------- FUSED init: deg | prep | cnt_valid | zero cursor/tctr ----------------

__global__ __launch_bounds__(256) void k_init(const int* __restrict__ edst, int* __restrict__ degi,
                                              const float* __restrict__ conv2_w, const float* __restrict__ np1_w,
                                              const float* __restrict__ np2_w, const float* __restrict__ src_w,
                                              const float* __restrict__ tgt_w, const float* __restrict__ inv1_w,
                                              const float* __restrict__ np1_b, const float* __restrict__ inv1_b,
                                              const float* __restrict__ z, float* __restrict__ T,
                                              float* __restrict__ c1, float* __restrict__ cz,
                                              const int* __restrict__ depth, const float* __restrict__ x,
                                              int* __restrict__ cnt, float* __restrict__ out,
                                              int* __restrict__ cursor, int* __restrict__ tctr) {
    int b = blockIdx.x;
    int tid = threadIdx.x;
    if (b < 512) {                         // ---- degree ----
        int t = b * 256 + tid;
        atomicAdd(&degi[edst[t]], 1);
    } else if (b < 1024) {                 // ---- weight prep ----
        int tb = b - 512;
        int y = tb >> 6, xb = tb & 63;
        if (y < 7) {
            int t = xb * 256 + tid;
            int j = t >> 7, k = t & 127;
            const float* W; int stride, off;
            switch (y) {
                case 0:  W = conv2_w; stride = 128; off = 0;   break;
                case 1:  W = np1_w;   stride = 256; off = 0;   break;
                case 2:  W = np2_w;   stride = 128; off = 0;   break;
                case 3:  W = src_w;   stride = 128; off = 0;   break;
                case 4:  W = tgt_w;   stride = 128; off = 0;   break;
                case 5:  W = inv1_w;  stride = 384; off = 0;   break;
                default: W = inv1_w;  stride = 384; off = 128; break;
            }
            T[y * 16384 + k * 128 + j] = W[j * stride + off + k];
        } else if (xb == 0) {
            if (tid < 128) {
                float s = np1_b[tid];
                for (int k = 0; k < 128; k++) s += z[k] * np1_w[tid * 256 + 128 + k];
                c1[tid] = s;
            } else {
                int j = tid - 128;
                float s = inv1_b[j];
                for (int k = 0; k < 128; k++) s += z[k] * inv1_w[j * 384 + 256 + k];
                cz[j] = s;
            }
        }
    } else if (b < 1056) {                 // ---- cnt + valid flags ----
        int v = (b - 1024) * 256 + tid;
        int limit = depth[v] + 1;   // depth[v]-1+DEPTH_PERTURB
        int lo = 0, hi = NN;
        while (lo < hi) { int mid = (lo + hi) >> 1; if (depth[mid] <= limit) lo = mid + 1; else hi = mid; }
        cnt[v] = lo;
        int type = (int)(x[v * 2] + 0.5f);
        bool tv = (depth[v] >= 1) && (type != 0);
        out[4 * NN * 2 + v * 2 + 0] = (tv && lo >= 1) ? 1.0f : 0.0f;
        out[4 * NN * 2 + v * 2 + 1] = (tv && type == 2 && lo >= 2) ? 1.0f : 0.0f;
    } else {                               // ---- zero cursor + tctr ----
#pragma unroll
        for (int i = 0; i < 32; i++) cursor[i * 256 + tid] = 0;
        if (tid == 0) *tctr = 0;
    }
}

// ---------------- FUSED: scan (block 0) | tiles (block 1) ----------------

__global__ __launch_bounds__(1024) void k_scan_tiles(const int* __restrict__ degi, int* __restrict__ rowptr,
                                                     float* __restrict__ dinv, float* __restrict__ rsq,
                                                     const int* __restrict__ cnt, int* __restrict__ nact,
                                                     int* __restrict__ tlist, int* __restrict__ ntiles) {
    if (blockIdx.x == 0) {
        __shared__ int ls[1024];
        int tid = threadIdx.x;
        int base = tid * 8;
        int loc[8]; int s = 0;
#pragma unroll
        for (int i = 0; i < 8; i++) {
            int dg = degi[base + i];
            loc[i] = s; s += dg;
            double d = (double)(dg + 1);
            dinv[base + i] = (float)(1.0 / d);
            rsq[base + i] = (float)(1.0 / sqrt(d));
        }
        ls[tid] = s; __syncthreads();
        int tot = s;
        for (int d = 1; d < 1024; d <<= 1) {
            int v = (tid >= d) ? ls[tid - d] : 0;
            __syncthreads();
            ls[tid] += v;
            __syncthreads();
        }
        int pre = ls[tid] - tot;
#pragma unroll
        for (int i = 0; i < 8; i++) rowptr[base + i] = pre + loc[i];
        if (tid == 1023) rowptr[NN] = pre + tot;
    } else {
        int lane = threadIdx.x;   // one wave does the tile list
        if (lane >= 64) return;
        int cmax = cnt[lane * VT + VT - 1];
        int n = (cmax + SEG - 1) / SEG;   // <= 64
        nact[lane] = n;
        int x = n;
        for (int off = 1; off < 64; off <<= 1) {
            int y = __shfl_up(x, off, 64);
            if (lane >= off) x += y;
        }
        int base = x - n;
        for (int s = 0; s < n; s++) tlist[base + s] = (lane << 8) | s;
        if (lane == 63) *ntiles = x;
    }
}

__global__ __launch_bounds__(256) void k_fill(const int* __restrict__ src, const int* __restrict__ dst,
                                              const int* __restrict__ rowptr, int* __restrict__ cursor,
                                              int* __restrict__ ecsr) {
    int t = blockIdx.x * 256 + threadIdx.x;
    if (t < EE) {
        int d = dst[t];
        int pos = atomicAdd(&cursor[d], 1);
        ecsr[rowptr[d] + pos] = src[t];
    }
}

// ---------------- FUSED GCN layer 1 + xw2 GEMM: h1 stays in LDS ----------------

__global__ __launch_bounds__(256) void k_gather1xw(const int* __restrict__ rowptr, const int* __restrict__ ecsr,
                                                   const float* __restrict__ rsq, const float* __restrict__ dinv,
                                                   const float* __restrict__ x, const float* __restrict__ w,
                                                   const float* __restrict__ bias, const float* __restrict__ T0,
                                                   float* __restrict__ xw2) {
    __shared__ float h1s[4][128];
    int tid = threadIdx.x;
    int g = blockIdx.x * 256 + tid;
    int d = g >> 6, lane = g & 63, wv = tid >> 6;
    {
        float w0a = w[lane * 2], w1a = w[lane * 2 + 1];
        float w0b = w[(lane + 64) * 2], w1b = w[(lane + 64) * 2 + 1];
        int s0 = rowptr[d], s1 = rowptr[d + 1];
        float rd = rsq[d];
        float a0 = 0.f, a1 = 0.f;
        for (int sl = s0; sl < s1; sl++) {
            int s = ecsr[sl];
            float x0 = x[s * 2], x1 = x[s * 2 + 1];
            float f = rsq[s] * rd;
            a0 = fmaf(f, x0 * w0a + x1 * w1a, a0);
            a1 = fmaf(f, x0 * w0b + x1 * w1b, a1);
        }
        float x0d = x[d * 2], x1d = x[d * 2 + 1], di = dinv[d];
        a0 = fmaf(x0d * w0a + x1d * w1a, di, a0) + bias[lane];
        a1 = fmaf(x0d * w0b + x1d * w1b, di, a1) + bias[64 + lane];
        h1s[wv][lane] = fmaxf(a0, 0.f);
        h1s[wv][64 + lane] = fmaxf(a1, 0.f);
    }
    __syncthreads();
    // xw2 for the block's 4 rows: thread -> col j, rows r0 and r0+2
    int j = tid & 127, r0 = tid >> 7;
    int dbase = blockIdx.x * 4;
    float acc0 = 0.f, acc1 = 0.f;
#pragma unroll 8
    for (int k = 0; k < 128; k++) {
        float t0 = T0[k * 128 + j];
        acc0 = fmaf(h1s[r0][k], t0, acc0);
        acc1 = fmaf(h1s[r0 + 2][k], t0, acc1);
    }
    xw2[(size_t)(dbase + r0) * HH + j] = acc0;
    xw2[(size_t)(dbase + r0 + 2) * HH + j] = acc1;
}

// ---------------- FUSED GCN layer 2 + MLP: gather h2 straight into the LDS tile ----------------
// h2's ONLY consumer was k_mlp (h3 overwrote it in-place). The per-row gather here is the
// verbatim k_gather2 body (same fmaf order per (d,lane)) writing bufA instead of global ->
// h2 values bit-identical -> everything downstream bit-identical. Kills one dispatch + the
// 8 MB h2 round-trip. NOTE: xw2 now lives in the pval region (wsf+4NH) because this kernel
// reads xw2 while writing the planes that occupied xw2's old R1 slot.

__global__ __launch_bounds__(256) void k_mlp(const int* __restrict__ rowptr, const int* __restrict__ ecsr,
                                             const float* __restrict__ rsq, const float* __restrict__ dinv,
                                             const float* __restrict__ xw, const float* __restrict__ bias2,
                                             const float* __restrict__ T,
                                             const float* __restrict__ c1, const float* __restrict__ np2_b,
                                             float* __restrict__ h3g,
                                             unsigned short* __restrict__ HtP, unsigned short* __restrict__ HsP) {
    __shared__ float bufA[16][132];
    __shared__ float bufB[16][132];
    __shared__ float Bs[32][128];
    int tid = threadIdx.x;
    int tx = tid & 31, ty = tid >> 5;   // ty 0..7 -> rows ty*2, ty*2+1
    int row0 = blockIdx.x * 16;
    // ---- gather phase: 4 waves x 4 rows, k_gather2 body verbatim, h2 -> bufA ----
    {
        int wv = tid >> 6, lane = tid & 63;
#pragma unroll
        for (int r = 0; r < 4; r++) {
            int dl = wv * 4 + r;
            int d = row0 + dl;
            int s0 = rowptr[d], s1 = rowptr[d + 1];
            float rd = rsq[d];
            float a0 = 0.f, a1 = 0.f;
            for (int sl = s0; sl < s1; sl++) {
                int s = ecsr[sl];                       // wave-uniform scalar load
                float f = rsq[s] * rd;
                a0 = fmaf(f, xw[s * HH + lane], a0);    // coalesced 256B row segment
                a1 = fmaf(f, xw[s * HH + 64 + lane], a1);
            }
            float di = dinv[d];
            a0 = fmaf(xw[d * HH + lane], di, a0) + bias2[lane];
            a1 = fmaf(xw[d * HH + 64 + lane], di, a1) + bias2[64 + lane];
            bufA[dl][lane] = fmaxf(a0, 0.f);
            bufA[dl][64 + lane] = fmaxf(a1, 0.f);
        }
    }
    __syncthreads();
    for (int g = 0; g < 4; g++) {
        const float* WT;
        switch (g) {
            case 0:  WT = T + 1 * 16384; break;   // np1 (h-part)
            case 1:  WT = T + 2 * 16384; break;   // np2
            case 2:  WT = T + 4 * 16384; break;   // tgt -> Ht
            default: WT = T + 3 * 16384; break;   // src -> Hs
        }
        float (*src)[132] = (g == 1) ? bufB : bufA;
        float acc[2][4] = {};
        for (int k0 = 0; k0 < 128; k0 += 32) {
#pragma unroll
            for (int i = 0; i < 4; i++) {
                int kk = (tid >> 5) + i * 8;
                int c = (tid & 31) << 2;
                *(float4*)&Bs[kk][c] = *(const float4*)&WT[(k0 + kk) * HH + c];
            }
            __syncthreads();
#pragma unroll 8
            for (int kk = 0; kk < 32; kk++) {
                float a0 = src[ty * 2 + 0][k0 + kk], a1 = src[ty * 2 + 1][k0 + kk];
                float4 b = *(const float4*)&Bs[kk][tx * 4];
                acc[0][0] = fmaf(a0, b.x, acc[0][0]); acc[0][1] = fmaf(a0, b.y, acc[0][1]);
                acc[0][2] = fmaf(a0, b.z, acc[0][2]); acc[0][3] = fmaf(a0, b.w, acc[0][3]);
                acc[1][0] = fmaf(a1, b.x, acc[1][0]); acc[1][1] = fmaf(a1, b.y, acc[1][1]);
                acc[1][2] = fmaf(a1, b.z, acc[1][2]); acc[1][3] = fmaf(a1, b.w, acc[1][3]);
            }
            __syncthreads();
        }
        if (g == 0) {          // t = relu(. + c1) -> bufB
#pragma unroll
            for (int i = 0; i < 2; i++)
#pragma unroll
                for (int jj = 0; jj < 4; jj++)
                    bufB[ty * 2 + i][tx * 4 + jj] = fmaxf(acc[i][jj] + c1[tx * 4 + jj], 0.f);
        } else if (g == 1) {   // h3 = . + np2_b -> bufA + global
#pragma unroll
            for (int i = 0; i < 2; i++) {
                float4 v;
                v.x = acc[i][0] + np2_b[tx * 4 + 0];
                v.y = acc[i][1] + np2_b[tx * 4 + 1];
                v.z = acc[i][2] + np2_b[tx * 4 + 2];
                v.w = acc[i][3] + np2_b[tx * 4 + 3];
                bufA[ty * 2 + i][tx * 4 + 0] = v.x; bufA[ty * 2 + i][tx * 4 + 1] = v.y;
                bufA[ty * 2 + i][tx * 4 + 2] = v.z; bufA[ty * 2 + i][tx * 4 + 3] = v.w;
                *(float4*)&h3g[(size_t)(row0 + ty * 2 + i) * HH + tx * 4] = v;
            }
        } else {               // split-bf16 3-plane emission, node-major rows
            unsigned short* PP = (g == 2) ? HtP : HsP;
            int chunk = tx >> 3;
            int cic = (tx * 4) & 31;
#pragma unroll
            for (int i = 0; i < 2; i++) {
                int row = row0 + ty * 2 + i;
                size_t off = (size_t)row * 384 + chunk * 96 + cic;
                unsigned short h[4], m[4], lo[4];
#pragma unroll
                for (int jj = 0; jj < 4; jj++) {
                    float val = acc[i][jj];
                    unsigned short hb = f2bf(val);
                    float r1 = val - bf2f(hb);
                    unsigned short mb = f2bf(r1);
                    float r2 = r1 - bf2f(mb);
                    h[jj] = hb; m[jj] = mb; lo[jj] = f2bf(r2);
                }
                *(uint2*)&PP[off] = make_uint2((unsigned)h[0] | ((unsigned)h[1] << 16),
                                               (unsigned)h[2] | ((unsigned)h[3] << 16));
                *(uint2*)&PP[off + 32] = make_uint2((unsigned)m[0] | ((unsigned)m[1] << 16),
                                                    (unsigned)m[2] | ((unsigned)m[3] << 16));
                *(uint2*)&PP[off + 64] = make_uint2((unsigned)lo[0] | ((unsigned)lo[1] << 16),
                                                    (unsigned)lo[2] | ((unsigned)lo[3] << 16));
            }
        }
    }
}

// ---------------- fused P/Q: [8192x128] @ {T5,T6}, 16-row tiles, A loaded once ----------------

__global__ __launch_bounds__(256) void k_gemmPQ(const float* __restrict__ A, const float* __restrict__ WT0,
                                                const float* __restrict__ WT1,
                                                float* __restrict__ P, float* __restrict__ Q) {
    __shared__ float As[16][132];
    __shared__ float Bs[32][128];
    int tid = threadIdx.x;
    int tx = tid & 31, ty = tid >> 5;
    int row0 = blockIdx.x * 16;
#pragma unroll
    for (int p = 0; p < 2; p++) {
        int q = p * 256 + tid;
        int r = q >> 5, c4 = (q & 31) * 4;
        *(float4*)&As[r][c4] = *(const float4*)&A[(size_t)(row0 + r) * HH + c4];
    }
    __syncthreads();
    for (int m = 0; m < 2; m++) {
        const float* WT = m ? WT1 : WT0;
        float* outp = m ? Q : P;
        float acc[2][4] = {};
        for (int k0 = 0; k0 < 128; k0 += 32) {
#pragma unroll
            for (int i = 0; i < 4; i++) {
                int kk = (tid >> 5) + i * 8;
                int c = (tid & 31) << 2;
                *(float4*)&Bs[kk][c] = *(const float4*)&WT[(k0 + kk) * HH + c];
            }
            __syncthreads();
#pragma unroll 8
            for (int kk = 0; kk < 32; kk++) {
                float a0 = As[ty * 2 + 0][k0 + kk], a1 = As[ty * 2 + 1][k0 + kk];
                float4 b = *(const float4*)&Bs[kk][tx * 4];
                acc[0][0] = fmaf(a0, b.x, acc[0][0]); acc[0][1] = fmaf(a0, b.y, acc[0][1]);
                acc[0][2] = fmaf(a0, b.z, acc[0][2]); acc[0][3] = fmaf(a0, b.w, acc[0][3]);
                acc[1][0] = fmaf(a1, b.x, acc[1][0]); acc[1][1] = fmaf(a1, b.y, acc[1][1]);
                acc[1][2] = fmaf(a1, b.z, acc[1][2]); acc[1][3] = fmaf(a1, b.w, acc[1][3]);
            }
            __syncthreads();
        }
#pragma unroll
        for (int i = 0; i < 2; i++) {
            *(float4*)&outp[(size_t)(row0 + ty * 2 + i) * HH + tx * 4] =
                make_float4(acc[i][0], acc[i][1], acc[i][2], acc[i][3]);
        }
    }
}

// ---------------- fused masked GEMM + top-2 (stage 1) — R8 structure, frozen ----------------

__device__ __forceinline__ void stage32(unsigned short* buf, const unsigned short* __restrict__ HsP,
                                        int cb, int wave, int lane) {
    if (lane < 48) {   // 48 lanes x 16 B = 768 B = one plane row; 8 waves x 4 rows = 32
        const unsigned short* g0 = HsP + (size_t)(cb + wave * 4) * 384 + lane * 8;
        unsigned short* l0 = buf + wave * 4 * 392;
#pragma unroll
        for (int k = 0; k < 4; k++) {
            __builtin_amdgcn_global_load_lds((const AS1U*)(g0 + (size_t)k * 384),
                                             (AS3U*)(l0 + k * 392), 16, 0, 0);
        }
    }
}

__global__ __launch_bounds__(512, 4) void k_top2_stage1(
    const unsigned short* __restrict__ HtP, const unsigned short* __restrict__ HsP,
    const int* __restrict__ cnt, const int* __restrict__ tlist,
    const int* __restrict__ ntiles, int* __restrict__ tctr,
    float* __restrict__ pval, int* __restrict__ pidx) {
    __shared__ unsigned short Bsh[2][32 * 392];   // 2 x (32 u-rows x 784 B) = 50,176 B
    __shared__ int tsh;
    int tid = threadIdx.x;
    int wave = tid >> 6, lane = tid & 63;
    int l = lane & 15, quad = lane >> 4;
    int nt = *ntiles;
    for (;;) {
        if (tid == 0) tsh = atomicAdd(tctr, 1);
        __syncthreads();
        int t = tsh;
        if (t >= nt) return;
        int code = tlist[t];
        int v0 = (code >> 8) * VT;
        int seg = code & 255;
        int ub0 = seg * SEG;
        int vbase = v0 + wave * 16;   // 8 waves x 16 rows = 128-row tile
        int cmax = cnt[v0 + VT - 1];
        int uend = ub0 + SEG; if (uend > cmax) uend = cmax;
        int nch = (uend - ub0 + 31) >> 5;   // 32-row chunks in this tile (1..4)
        stage32(Bsh[0], HsP, ub0, wave, lane);
        bf16x8 afr[4][3];
        {
            const unsigned short* ap = &HtP[(size_t)(vbase + l) * 384 + quad * 8];
#pragma unroll
            for (int c = 0; c < 4; c++) {
                afr[c][0] = *(const bf16x8*)&ap[c * 96];
                afr[c][1] = *(const bf16x8*)&ap[c * 96 + 32];
                afr[c][2] = *(const bf16x8*)&ap[c * 96 + 64];
            }
        }
        int creg[4];
#pragma unroll
        for (int i = 0; i < 4; i++)
            creg[i] = cnt[vbase + quad * 4 + i];
        int wmax = cnt[vbase + 15];   // wave-uniform max candidate count for these 16 rows
        float t1v[4], t2v[4]; int t1i[4], t2i[4];
#pragma unroll
        for (int i = 0; i < 4; i++) { t1v[i] = NEGV; t2v[i] = NEGV; t1i[i] = 0x7fffffff; t2i[i] = 0x7fffffff; }
        __syncthreads();   // chunk 0 resident
        for (int ci = 0; ci < nch; ci++) {
            int cb = ub0 + ci * 32;
            if (ci + 1 < nch) stage32(Bsh[(ci + 1) & 1], HsP, cb + 32, wave, lane);   // async prefetch
            const unsigned short* bbase = Bsh[ci & 1];
            int cend = cb + 32; if (cend > uend) cend = uend;
            for (int u0 = cb; u0 < cend; u0 += 16) {
                if (u0 >= wmax) break;   // wave-uniform skip: fully masked for these rows
                int u = u0 + l;
                const unsigned short* bp = &bbase[(u0 - cb + l) * 392 + quad * 8];
                f32x4 acc0 = {0.f, 0.f, 0.f, 0.f};
#pragma unroll
                for (int c = 0; c < 4; c++) {
                    bf16x8 bh = *(const bf16x8*)&bp[c * 96];
                    bf16x8 bm = *(const bf16x8*)&bp[c * 96 + 32];
                    bf16x8 bl = *(const bf16x8*)&bp[c * 96 + 64];
                    acc0 = __builtin_amdgcn_mfma_f32_16x16x32_bf16(afr[c][0], bh, acc0, 0, 0, 0);
                    acc0 = __builtin_amdgcn_mfma_f32_16x16x32_bf16(afr[c][0], bm, acc0, 0, 0, 0);
                    acc0 = __builtin_amdgcn_mfma_f32_16x16x32_bf16(afr[c][1], bh, acc0, 0, 0, 0);
                    acc0 = __builtin_amdgcn_mfma_f32_16x16x32_bf16(afr[c][0], bl, acc0, 0, 0, 0);
                    acc0 = __builtin_amdgcn_mfma_f32_16x16x32_bf16(afr[c][2], bh, acc0, 0, 0, 0);
                    acc0 = __builtin_amdgcn_mfma_f32_16x16x32_bf16(afr[c][1], bm, acc0, 0, 0, 0);
                }
#pragma unroll
                for (int i = 0; i < 4; i++) {
                    float sv = acc0[i];
                    bool gt1 = (u < creg[i]) & (sv > t1v[i]);
                    bool gt2 = (u < creg[i]) & (sv > t2v[i]);
                    float n2v = gt1 ? t1v[i] : (gt2 ? sv : t2v[i]);
                    int   n2i = gt1 ? t1i[i] : (gt2 ? u  : t2i[i]);
                    t1v[i] = gt1 ? sv : t1v[i];
                    t1i[i] = gt1 ? u  : t1i[i];
                    t2v[i] = n2v; t2i[i] = n2i;
                }
            }
            __syncthreads();   // drains prefetch DMA + all waves done reading Bsh[ci&1]
        }
#pragma unroll
        for (int m = 1; m <= 8; m <<= 1) {
#pragma unroll
            for (int i = 0; i < 4; i++) {
                float ov1 = __shfl_xor(t1v[i], m, 64);
                int   oi1 = __shfl_xor(t1i[i], m, 64);
                float ov2 = __shfl_xor(t2v[i], m, 64);
                int   oi2 = __shfl_xor(t2i[i], m, 64);
                bool b1 = (ov1 > t1v[i]) || (ov1 == t1v[i] && oi1 < t1i[i]);
                float w1v = b1 ? ov1 : t1v[i]; int w1i = b1 ? oi1 : t1i[i];
                float l1v = b1 ? t1v[i] : ov1; int l1i = b1 ? t1i[i] : oi1;
                float c2v = b1 ? ov2 : t2v[i]; int c2i = b1 ? oi2 : t2i[i];
                bool b2 = (l1v > c2v) || (l1v == c2v && l1i < c2i);
                t1v[i] = w1v; t1i[i] = w1i;
                t2v[i] = b2 ? l1v : c2v; t2i[i] = b2 ? l1i : c2i;
            }
        }
        if (l == 0) {
#pragma unroll
            for (int i = 0; i < 4; i++) {
                int v = vbase + quad * 4 + i;
                int o = (v * NSEG + seg) * 2;
                pval[o] = t1v[i];     pidx[o] = t1i[i];
                pval[o + 1] = t2v[i]; pidx[o + 1] = t2i[i];
            }
        }
        // no top-of-loop barrier: this tile's final chunk barrier already ordered all
        // tsh reads and Bsh reads before the next tile's tsh write / chunk-0 DMA.
    }
}

// ---------------- fused merge + inversion epilogue: one wave per v (thin, P/Q-reading) ----------------

__global__ __launch_bounds__(256) void k_merge_inv(const float* __restrict__ pval, const int* __restrict__ pidx,
                                                   const int* __restrict__ nact,
                                                   const float* __restrict__ P, const float* __restrict__ Q,
                                                   const float* __restrict__ cz, const float* __restrict__ w2,
                                                   const float* __restrict__ b2, float* __restrict__ out) {
    int gid = blockIdx.x * 256 + threadIdx.x;
    int v = gid >> 6, lane = gid & 63;
    if (v >= NN) return;
    int na = nact[v >> 7];
    float v1 = NEGV, v2 = NEGV; int i1 = 0x7fffffff, i2 = 0x7fffffff;
    if (lane < na) {
        int o = (v * NSEG + lane) * 2;
        v1 = pval[o];     i1 = pidx[o];
        v2 = pval[o + 1]; i2 = pidx[o + 1];
    }
#pragma unroll
    for (int m = 1; m <= 32; m <<= 1) {
        float ov1 = __shfl_xor(v1, m, 64);
        int   oi1 = __shfl_xor(i1, m, 64);
        float ov2 = __shfl_xor(v2, m, 64);
        int   oi2 = __shfl_xor(i2, m, 64);
        bool b1 = (ov1 > v1) || (ov1 == v1 && oi1 < i1);
        float w1v = b1 ? ov1 : v1; int w1i = b1 ? oi1 : i1;
        float l1v = b1 ? v1 : ov1; int l1i = b1 ? i1 : oi1;
        float c2v = b1 ? ov2 : v2; int c2i = b1 ? oi2 : i2;
        bool b2 = (l1v > c2v) || (l1v == c2v && l1i < c2i);
        v1 = w1v; i1 = w1i;
        v2 = b2 ? l1v : c2v; i2 = b2 ? l1i : c2i;
    }
    // resolve NEGV sentinels (matches reference top_k over all-NEG candidates: lowest indices)
    if (v1 == NEGV) { v2 = NEGV; i1 = 0; i2 = 1; }
    else if (v2 == NEGV) { i2 = (i1 == 0) ? 1 : 0; }
    int u1 = i1, u2 = i2;   // now always in [0, NN)
    float cza = cz[lane], czb = cz[64 + lane];
    float w2a = w2[lane], w2b = w2[64 + lane];
    float Qa = Q[(size_t)v * HH + lane], Qb = Q[(size_t)v * HH + 64 + lane];
    float p0 = fmaxf(P[(size_t)u1 * HH + lane] + Qa + cza, 0.f) * w2a +
               fmaxf(P[(size_t)u1 * HH + 64 + lane] + Qb + czb, 0.f) * w2b;
    float p1 = fmaxf(P[(size_t)u2 * HH + lane] + Qa + cza, 0.f) * w2a +
               fmaxf(P[(size_t)u2 * HH + 64 + lane] + Qb + czb, 0.f) * w2b;
#pragma unroll
    for (int off = 32; off >= 1; off >>= 1) {
        p0 += __shfl_down(p0, off, 64);
        p1 += __shfl_down(p1, off, 64);
    }
    if (lane == 0) {
        float bb = b2[0];
        float l0 = p0 + bb, l1 = p1 + bb;
        out[v * 2 + 0] = v1; out[v * 2 + 1] = v2;                 // top_vals
        out[NN * 2 + v * 2 + 0] = l0;                             // inv_logit
        out[NN * 2 + v * 2 + 1] = l1;
        out[2 * NN * 2 + v * 2 + 0] = (float)i1;                  // top_idx
        out[2 * NN * 2 + v * 2 + 1] = (float)i2;
        out[3 * NN * 2 + v * 2 + 0] = (l0 > 0.f) ? 1.f : 0.f;     // inv_bit
        out[3 * NN * 2 + v * 2 + 1] = (l1 > 0.f) ? 1.f : 0.f;
    }
}

// ---------------- launch ----------------

extern "C" void kernel_launch(void* const* d_in, const int* in_sizes, int n_in,
                              void* d_out, int out_size, void* d_ws, size_t ws_size,
                              hipStream_t stream) {
    const float* x       = (const float*)d_in[0];
    const float* z       = (const float*)d_in[1];
    const int*   eidx    = (const int*)d_in[2];
    const int*   depth   = (const int*)d_in[3];
    const float* conv1_w = (const float*)d_in[4];
    const float* conv1_b = (const float*)d_in[5];
    const float* conv2_w = (const float*)d_in[6];
    const float* conv2_b = (const float*)d_in[7];
    const float* np1_w   = (const float*)d_in[8];
    const float* np1_b   = (const float*)d_in[9];
    const float* np2_w   = (const float*)d_in[10];
    const float* np2_b   = (const float*)d_in[11];
    const float* src_w   = (const float*)d_in[12];
    const float* tgt_w   = (const float*)d_in[13];
    const float* inv1_w  = (const float*)d_in[14];
    const float* inv1_b  = (const float*)d_in[15];
    const float* inv2_w  = (const float*)d_in[16];
    const float* inv2_b  = (const float*)d_in[17];
    float* out = (float*)d_out;
    float* wsf = (float*)d_ws;

    const int NH = NN * HH;   // 1,048,576 floats = 4 MB
    float* R0 = wsf;                          // h3
    float* R1 = wsf + (size_t)NH;             // planes / (P,Q after stage1)
    unsigned short* HtP = (unsigned short*)R1;
    unsigned short* HsP = HtP + 3 * (size_t)NH;
    float* P = wsf + (size_t)NH;              // aliases planes — written AFTER stage1
    float* Q = wsf + 2 * (size_t)NH;
    float* XW2 = wsf + 4 * (size_t)NH;        // xw2 (pval region — dead until stage1 writes pval)
    float* pval = wsf + 4 * (size_t)NH;
    int*   pidx = (int*)(wsf + 5 * (size_t)NH);
    float* T  = wsf + 6 * (size_t)NH;
    float* c1 = T + 7 * 16384;
    float* cz = c1 + 128;
    float* rsq  = cz + 128;
    float* dinv = rsq + NN;
    int* degi   = (int*)(dinv + NN);
    int* rowptr = degi + NN;             // NN+1
    int* cursor = rowptr + NN + 1;
    int* cnt    = cursor + NN;
    int* nact   = cnt + NN;              // 64
    int* ntiles = nact + 64;
    int* tctr   = ntiles + 1;
    int* tlist  = tctr + 1;              // <= 4096
    int* ecsr   = tlist + 4096;          // EE

    const int* esrc = eidx;
    const int* edst = eidx + EE;

    hipMemsetAsync(degi, 0, NN * sizeof(int), stream);
    k_init<<<1057, 256, 0, stream>>>(edst, degi, conv2_w, np1_w, np2_w, src_w, tgt_w, inv1_w,
                                     np1_b, inv1_b, z, T, c1, cz, depth, x, cnt, out, cursor, tctr);
    k_scan_tiles<<<2, 1024, 0, stream>>>(degi, rowptr, dinv, rsq, cnt, nact, tlist, ntiles);
    k_fill<<<EE / 256, 256, 0, stream>>>(esrc, edst, rowptr, cursor, ecsr);
    k_gather1xw<<<NN * 64 / 256, 256, 0, stream>>>(rowptr, ecsr, rsq, dinv, x, conv1_w, conv1_b,
                                                   T + 0 * 16384, XW2);                // xw2
    k_mlp<<<512, 256, 0, stream>>>(rowptr, ecsr, rsq, dinv, XW2, conv2_b, T, c1, np2_b,
                                   R0, HtP, HsP);   // h2 (in-LDS) -> h3 + planes
    k_top2_stage1<<<768, 512, 0, stream>>>(HtP, HsP, cnt, tlist, ntiles, tctr, pval, pidx);
    k_gemmPQ<<<512, 256, 0, stream>>>(R0, T + 5 * 16384, T + 6 * 16384, P, Q);   // P,Q = h3@inv1{a,b}^T
    k_merge_inv<<<NN / 4, 256, 0, stream>>>(pval, pidx, nact, P, Q, cz, inv2_w, inv2_b, out);
}

// Round 12
// 280.986 us; speedup vs baseline: 1.0479x; 1.0479x over previous
//
#include <hip/hip_runtime.h>

#define NN 8192
#define EE 131072
#define HH 128
#define NEGV -1.0e30f
#define SEG 128
#define NSEG (NN / SEG)   // 64
#define VT 128            // v-rows per stage1 block (8 waves x 16)

typedef __attribute__((ext_vector_type(8))) short bf16x8;
typedef __attribute__((ext_vector_type(4))) float f32x4;

typedef __attribute__((address_space(1))) unsigned int AS1U;
typedef __attribute__((address_space(3))) unsigned int AS3U;

__device__ __forceinline__ unsigned short f2bf(float f) {
    unsigned int u = __float_as_uint(f);
    unsigned int r = u + 0x7fffu + ((u >> 16) & 1u);
    return (unsigned short)(r >> 16);
}
__device__ __forceinline__ float bf2f(unsigned short b) {
    return __uint_as_float((unsigned int)b << 16);
}

// ---------------- FUSED init: deg | prep | cnt_valid | zero cursor/tctr ----------------

__global__ __launch_bounds__(256) void k_init(const int* __restrict__ edst, int* __restrict__ degi,
                                              const float* __restrict__ conv2_w, const float* __restrict__ np1_w,
                                              const float* __restrict__ np2_w, const float* __restrict__ src_w,
                                              const float* __restrict__ tgt_w, const float* __restrict__ inv1_w,
                                              const float* __restrict__ np1_b, const float* __restrict__ inv1_b,
                                              const float* __restrict__ z, float* __restrict__ T,
                                              float* __restrict__ c1, float* __restrict__ cz,
                                              const int* __restrict__ depth, const float* __restrict__ x,
                                              int* __restrict__ cnt, float* __restrict__ out,
                                              int* __restrict__ cursor, int* __restrict__ tctr) {
    int b = blockIdx.x;
    int tid = threadIdx.x;
    if (b < 512) {                         // ---- degree ----
        int t = b * 256 + tid;
        atomicAdd(&degi[edst[t]], 1);
    } else if (b < 1024) {                 // ---- weight prep ----
        int tb = b - 512;
        int y = tb >> 6, xb = tb & 63;
        if (y < 7) {
            int t = xb * 256 + tid;
            int j = t >> 7, k = t & 127;
            const float* W; int stride, off;
            switch (y) {
                case 0:  W = conv2_w; stride = 128; off = 0;   break;
                case 1:  W = np1_w;   stride = 256; off = 0;   break;
                case 2:  W = np2_w;   stride = 128; off = 0;   break;
                case 3:  W = src_w;   stride = 128; off = 0;   break;
                case 4:  W = tgt_w;   stride = 128; off = 0;   break;
                case 5:  W = inv1_w;  stride = 384; off = 0;   break;
                default: W = inv1_w;  stride = 384; off = 128; break;
            }
            T[y * 16384 + k * 128 + j] = W[j * stride + off + k];
        } else if (xb == 0) {
            if (tid < 128) {
                float s = np1_b[tid];
                for (int k = 0; k < 128; k++) s += z[k] * np1_w[tid * 256 + 128 + k];
                c1[tid] = s;
            } else {
                int j = tid - 128;
                float s = inv1_b[j];
                for (int k = 0; k < 128; k++) s += z[k] * inv1_w[j * 384 + 256 + k];
                cz[j] = s;
            }
        }
    } else if (b < 1056) {                 // ---- cnt + valid flags ----
        int v = (b - 1024) * 256 + tid;
        int limit = depth[v] + 1;   // depth[v]-1+DEPTH_PERTURB
        int lo = 0, hi = NN;
        while (lo < hi) { int mid = (lo + hi) >> 1; if (depth[mid] <= limit) lo = mid + 1; else hi = mid; }
        cnt[v] = lo;
        int type = (int)(x[v * 2] + 0.5f);
        bool tv = (depth[v] >= 1) && (type != 0);
        out[4 * NN * 2 + v * 2 + 0] = (tv && lo >= 1) ? 1.0f : 0.0f;
        out[4 * NN * 2 + v * 2 + 1] = (tv && type == 2 && lo >= 2) ? 1.0f : 0.0f;
    } else {                               // ---- zero cursor + tctr ----
#pragma unroll
        for (int i = 0; i < 32; i++) cursor[i * 256 + tid] = 0;
        if (tid == 0) *tctr = 0;
    }
}

// ---------------- FUSED: scan (block 0) | tiles (block 1) ----------------

__global__ __launch_bounds__(1024) void k_scan_tiles(const int* __restrict__ degi, int* __restrict__ rowptr,
                                                     float* __restrict__ dinv, float* __restrict__ rsq,
                                                     const int* __restrict__ cnt, int* __restrict__ nact,
                                                     int* __restrict__ tlist, int* __restrict__ ntiles) {
    if (blockIdx.x == 0) {
        __shared__ int ls[1024];
        int tid = threadIdx.x;
        int base = tid * 8;
        int loc[8]; int s = 0;
#pragma unroll
        for (int i = 0; i < 8; i++) {
            int dg = degi[base + i];
            loc[i] = s; s += dg;
            double d = (double)(dg + 1);
            dinv[base + i] = (float)(1.0 / d);
            rsq[base + i] = (float)(1.0 / sqrt(d));
        }
        ls[tid] = s; __syncthreads();
        int tot = s;
        for (int d = 1; d < 1024; d <<= 1) {
            int v = (tid >= d) ? ls[tid - d] : 0;
            __syncthreads();
            ls[tid] += v;
            __syncthreads();
        }
        int pre = ls[tid] - tot;
#pragma unroll
        for (int i = 0; i < 8; i++) rowptr[base + i] = pre + loc[i];
        if (tid == 1023) rowptr[NN] = pre + tot;
    } else {
        int lane = threadIdx.x;   // one wave does the tile list
        if (lane >= 64) return;
        int cmax = cnt[lane * VT + VT - 1];
        int n = (cmax + SEG - 1) / SEG;   // <= 64
        nact[lane] = n;
        int x = n;
        for (int off = 1; off < 64; off <<= 1) {
            int y = __shfl_up(x, off, 64);
            if (lane >= off) x += y;
        }
        int base = x - n;
        for (int s = 0; s < n; s++) tlist[base + s] = (lane << 8) | s;
        if (lane == 63) *ntiles = x;
    }
}

__global__ __launch_bounds__(256) void k_fill(const int* __restrict__ src, const int* __restrict__ dst,
                                              const int* __restrict__ rowptr, int* __restrict__ cursor,
                                              int* __restrict__ ecsr) {
    int t = blockIdx.x * 256 + threadIdx.x;
    if (t < EE) {
        int d = dst[t];
        int pos = atomicAdd(&cursor[d], 1);
        ecsr[rowptr[d] + pos] = src[t];
    }
}

// ---------------- FUSED GCN layer 1 + xw2 GEMM: h1 stays in LDS ----------------

__global__ __launch_bounds__(256) void k_gather1xw(const int* __restrict__ rowptr, const int* __restrict__ ecsr,
                                                   const float* __restrict__ rsq, const float* __restrict__ dinv,
                                                   const float* __restrict__ x, const float* __restrict__ w,
                                                   const float* __restrict__ bias, const float* __restrict__ T0,
                                                   float* __restrict__ xw2) {
    __shared__ float h1s[4][128];
    int tid = threadIdx.x;
    int g = blockIdx.x * 256 + tid;
    int d = g >> 6, lane = g & 63, wv = tid >> 6;
    {
        float w0a = w[lane * 2], w1a = w[lane * 2 + 1];
        float w0b = w[(lane + 64) * 2], w1b = w[(lane + 64) * 2 + 1];
        int s0 = rowptr[d], s1 = rowptr[d + 1];
        float rd = rsq[d];
        float a0 = 0.f, a1 = 0.f;
        for (int sl = s0; sl < s1; sl++) {
            int s = ecsr[sl];
            float x0 = x[s * 2], x1 = x[s * 2 + 1];
            float f = rsq[s] * rd;
            a0 = fmaf(f, x0 * w0a + x1 * w1a, a0);
            a1 = fmaf(f, x0 * w0b + x1 * w1b, a1);
        }
        float x0d = x[d * 2], x1d = x[d * 2 + 1], di = dinv[d];
        a0 = fmaf(x0d * w0a + x1d * w1a, di, a0) + bias[lane];
        a1 = fmaf(x0d * w0b + x1d * w1b, di, a1) + bias[64 + lane];
        h1s[wv][lane] = fmaxf(a0, 0.f);
        h1s[wv][64 + lane] = fmaxf(a1, 0.f);
    }
    __syncthreads();
    // xw2 for the block's 4 rows: thread -> col j, rows r0 and r0+2
    int j = tid & 127, r0 = tid >> 7;
    int dbase = blockIdx.x * 4;
    float acc0 = 0.f, acc1 = 0.f;
#pragma unroll 8
    for (int k = 0; k < 128; k++) {
        float t0 = T0[k * 128 + j];
        acc0 = fmaf(h1s[r0][k], t0, acc0);
        acc1 = fmaf(h1s[r0 + 2][k], t0, acc1);
    }
    xw2[(size_t)(dbase + r0) * HH + j] = acc0;
    xw2[(size_t)(dbase + r0 + 2) * HH + j] = acc1;
}

// ---------------- GCN layer 2: gather over precomputed xw rows ----------------
// Kept as a standalone kernel: R11 proved fusing this latency-bound irregular gather into
// the mlp's GEMM blocks serializes worst-row latency onto every tile (+13 µs). As its own
// 2048-block dispatch it load-balances freely and overlaps neighbor kernels' ramp/tail.

__global__ __launch_bounds__(256) void k_gather2(const int* __restrict__ rowptr, const int* __restrict__ ecsr,
                                                 const float* __restrict__ rsq, const float* __restrict__ dinv,
                                                 const float* __restrict__ xw, const float* __restrict__ bias,
                                                 float* __restrict__ out) {
    int g = blockIdx.x * 256 + threadIdx.x;
    int d = g >> 6, lane = g & 63;
    if (d >= NN) return;
    int s0 = rowptr[d], s1 = rowptr[d + 1];
    float rd = rsq[d];
    float a0 = 0.f, a1 = 0.f;
    for (int sl = s0; sl < s1; sl++) {
        int s = ecsr[sl];                       // wave-uniform scalar load
        float f = rsq[s] * rd;
        a0 = fmaf(f, xw[s * HH + lane], a0);    // coalesced 256B row segment
        a1 = fmaf(f, xw[s * HH + 64 + lane], a1);
    }
    float di = dinv[d];
    a0 = fmaf(xw[d * HH + lane], di, a0) + bias[lane];
    a1 = fmaf(xw[d * HH + 64 + lane], di, a1) + bias[64 + lane];
    out[d * HH + lane] = fmaxf(a0, 0.f);
    out[d * HH + 64 + lane] = fmaxf(a1, 0.f);
}

// ---------------- fused MLP: h2 -> t -> h3 -> Ht/Hs planes — 16-ROW tiles ----------------

__global__ __launch_bounds__(256) void k_mlp(const float* __restrict__ h2g, const float* __restrict__ T,
                                             const float* __restrict__ c1, const float* __restrict__ np2_b,
                                             float* __restrict__ h3g,
                                             unsigned short* __restrict__ HtP, unsigned short* __restrict__ HsP) {
    __shared__ float bufA[16][132];
    __shared__ float bufB[16][132];
    __shared__ float Bs[32][128];
    int tid = threadIdx.x;
    int tx = tid & 31, ty = tid >> 5;   // ty 0..7 -> rows ty*2, ty*2+1
    int row0 = blockIdx.x * 16;
    // load h2 tile into bufA
#pragma unroll
    for (int p = 0; p < 2; p++) {
        int q = p * 256 + tid;
        int r = q >> 5, c4 = (q & 31) * 4;
        *(float4*)&bufA[r][c4] = *(const float4*)&h2g[(size_t)(row0 + r) * HH + c4];
    }
    __syncthreads();
    for (int g = 0; g < 4; g++) {
        const float* WT;
        switch (g) {
            case 0:  WT = T + 1 * 16384; break;   // np1 (h-part)
            case 1:  WT = T + 2 * 16384; break;   // np2
            case 2:  WT = T + 4 * 16384; break;   // tgt -> Ht
            default: WT = T + 3 * 16384; break;   // src -> Hs
        }
        float (*src)[132] = (g == 1) ? bufB : bufA;
        float acc[2][4] = {};
        for (int k0 = 0; k0 < 128; k0 += 32) {
#pragma unroll
            for (int i = 0; i < 4; i++) {
                int kk = (tid >> 5) + i * 8;
                int c = (tid & 31) << 2;
                *(float4*)&Bs[kk][c] = *(const float4*)&WT[(k0 + kk) * HH + c];
            }
            __syncthreads();
#pragma unroll 8
            for (int kk = 0; kk < 32; kk++) {
                float a0 = src[ty * 2 + 0][k0 + kk], a1 = src[ty * 2 + 1][k0 + kk];
                float4 b = *(const float4*)&Bs[kk][tx * 4];
                acc[0][0] = fmaf(a0, b.x, acc[0][0]); acc[0][1] = fmaf(a0, b.y, acc[0][1]);
                acc[0][2] = fmaf(a0, b.z, acc[0][2]); acc[0][3] = fmaf(a0, b.w, acc[0][3]);
                acc[1][0] = fmaf(a1, b.x, acc[1][0]); acc[1][1] = fmaf(a1, b.y, acc[1][1]);
                acc[1][2] = fmaf(a1, b.z, acc[1][2]); acc[1][3] = fmaf(a1, b.w, acc[1][3]);
            }
            __syncthreads();
        }
        if (g == 0) {          // t = relu(. + c1) -> bufB
#pragma unroll
            for (int i = 0; i < 2; i++)
#pragma unroll
                for (int jj = 0; jj < 4; jj++)
                    bufB[ty * 2 + i][tx * 4 + jj] = fmaxf(acc[i][jj] + c1[tx * 4 + jj], 0.f);
        } else if (g == 1) {   // h3 = . + np2_b -> bufA + global
#pragma unroll
            for (int i = 0; i < 2; i++) {
                float4 v;
                v.x = acc[i][0] + np2_b[tx * 4 + 0];
                v.y = acc[i][1] + np2_b[tx * 4 + 1];
                v.z = acc[i][2] + np2_b[tx * 4 + 2];
                v.w = acc[i][3] + np2_b[tx * 4 + 3];
                bufA[ty * 2 + i][tx * 4 + 0] = v.x; bufA[ty * 2 + i][tx * 4 + 1] = v.y;
                bufA[ty * 2 + i][tx * 4 + 2] = v.z; bufA[ty * 2 + i][tx * 4 + 3] = v.w;
                *(float4*)&h3g[(size_t)(row0 + ty * 2 + i) * HH + tx * 4] = v;
            }
        } else {               // split-bf16 3-plane emission, node-major rows
            unsigned short* PP = (g == 2) ? HtP : HsP;
            int chunk = tx >> 3;
            int cic = (tx * 4) & 31;
#pragma unroll
            for (int i = 0; i < 2; i++) {
                int row = row0 + ty * 2 + i;
                size_t off = (size_t)row * 384 + chunk * 96 + cic;
                unsigned short h[4], m[4], lo[4];
#pragma unroll
                for (int jj = 0; jj < 4; jj++) {
                    float val = acc[i][jj];
                    unsigned short hb = f2bf(val);
                    float r1 = val - bf2f(hb);
                    unsigned short mb = f2bf(r1);
                    float r2 = r1 - bf2f(mb);
                    h[jj] = hb; m[jj] = mb; lo[jj] = f2bf(r2);
                }
                *(uint2*)&PP[off] = make_uint2((unsigned)h[0] | ((unsigned)h[1] << 16),
                                               (unsigned)h[2] | ((unsigned)h[3] << 16));
                *(uint2*)&PP[off + 32] = make_uint2((unsigned)m[0] | ((unsigned)m[1] << 16),
                                                    (unsigned)m[2] | ((unsigned)m[3] << 16));
                *(uint2*)&PP[off + 64] = make_uint2((unsigned)lo[0] | ((unsigned)lo[1] << 16),
                                                    (unsigned)lo[2] | ((unsigned)lo[3] << 16));
            }
        }
    }
}

// ---------------- fused P/Q: [8192x128] @ {T5,T6}, 16-row tiles, A loaded once ----------------

__global__ __launch_bounds__(256) void k_gemmPQ(const float* __restrict__ A, const float* __restrict__ WT0,
                                                const float* __restrict__ WT1,
                                                float* __restrict__ P, float* __restrict__ Q) {
    __shared__ float As[16][132];
    __shared__ float Bs[32][128];
    int tid = threadIdx.x;
    int tx = tid & 31, ty = tid >> 5;
    int row0 = blockIdx.x * 16;
#pragma unroll
    for (int p = 0; p < 2; p++) {
        int q = p * 256 + tid;
        int r = q >> 5, c4 = (q & 31) * 4;
        *(float4*)&As[r][c4] = *(const float4*)&A[(size_t)(row0 + r) * HH + c4];
    }
    __syncthreads();
    for (int m = 0; m < 2; m++) {
        const float* WT = m ? WT1 : WT0;
        float* outp = m ? Q : P;
        float acc[2][4] = {};
        for (int k0 = 0; k0 < 128; k0 += 32) {
#pragma unroll
            for (int i = 0; i < 4; i++) {
                int kk = (tid >> 5) + i * 8;
                int c = (tid & 31) << 2;
                *(float4*)&Bs[kk][c] = *(const float4*)&WT[(k0 + kk) * HH + c];
            }
            __syncthreads();
#pragma unroll 8
            for (int kk = 0; kk < 32; kk++) {
                float a0 = As[ty * 2 + 0][k0 + kk], a1 = As[ty * 2 + 1][k0 + kk];
                float4 b = *(const float4*)&Bs[kk][tx * 4];
                acc[0][0] = fmaf(a0, b.x, acc[0][0]); acc[0][1] = fmaf(a0, b.y, acc[0][1]);
                acc[0][2] = fmaf(a0, b.z, acc[0][2]); acc[0][3] = fmaf(a0, b.w, acc[0][3]);
                acc[1][0] = fmaf(a1, b.x, acc[1][0]); acc[1][1] = fmaf(a1, b.y, acc[1][1]);
                acc[1][2] = fmaf(a1, b.z, acc[1][2]); acc[1][3] = fmaf(a1, b.w, acc[1][3]);
            }
            __syncthreads();
        }
#pragma unroll
        for (int i = 0; i < 2; i++) {
            *(float4*)&outp[(size_t)(row0 + ty * 2 + i) * HH + tx * 4] =
                make_float4(acc[i][0], acc[i][1], acc[i][2], acc[i][3]);
        }
    }
}

// ---------------- fused masked GEMM + top-2 (stage 1) — R8 32-row chunks + safe deltas ----------------

__device__ __forceinline__ void stage32(unsigned short* buf, const unsigned short* __restrict__ HsP,
                                        int cb, int wave, int lane) {
    if (lane < 48) {   // 48 lanes x 16 B = 768 B = one plane row; 8 waves x 4 rows = 32
        const unsigned short* g0 = HsP + (size_t)(cb + wave * 4) * 384 + lane * 8;
        unsigned short* l0 = buf + wave * 4 * 392;
#pragma unroll
        for (int k = 0; k < 4; k++) {
            __builtin_amdgcn_global_load_lds((const AS1U*)(g0 + (size_t)k * 384),
                                             (AS3U*)(l0 + k * 392), 16, 0, 0);
        }
    }
}

__global__ __launch_bounds__(512, 4) void k_top2_stage1(
    const unsigned short* __restrict__ HtP, const unsigned short* __restrict__ HsP,
    const int* __restrict__ cnt, const int* __restrict__ tlist,
    const int* __restrict__ ntiles, int* __restrict__ tctr,
    float* __restrict__ pval, int* __restrict__ pidx) {
    __shared__ unsigned short Bsh[2][32 * 392];   // 2 x (32 u-rows x 784 B) = 50,176 B
    __shared__ int tsh;
    int tid = threadIdx.x;
    int wave = tid >> 6, lane = tid & 63;
    int l = lane & 15, quad = lane >> 4;
    int nt = *ntiles;
    for (;;) {
        if (tid == 0) tsh = atomicAdd(tctr, 1);
        __syncthreads();
        int t = tsh;
        if (t >= nt) return;
        int code = tlist[t];
        int v0 = (code >> 8) * VT;
        int seg = code & 255;
        int ub0 = seg * SEG;
        int vbase = v0 + wave * 16;   // 8 waves x 16 rows = 128-row tile
        int cmax = cnt[v0 + VT - 1];
        int uend = ub0 + SEG; if (uend > cmax) uend = cmax;
        int nch = (uend - ub0 + 31) >> 5;   // 32-row chunks in this tile (1..4)
        stage32(Bsh[0], HsP, ub0, wave, lane);
        bf16x8 afr[4][3];
        {
            const unsigned short* ap = &HtP[(size_t)(vbase + l) * 384 + quad * 8];
#pragma unroll
            for (int c = 0; c < 4; c++) {
                afr[c][0] = *(const bf16x8*)&ap[c * 96];
                afr[c][1] = *(const bf16x8*)&ap[c * 96 + 32];
                afr[c][2] = *(const bf16x8*)&ap[c * 96 + 64];
            }
        }
        int creg[4];
#pragma unroll
        for (int i = 0; i < 4; i++)
            creg[i] = cnt[vbase + quad * 4 + i];
        int wmax = cnt[vbase + 15];   // wave-uniform max candidate count for these 16 rows
        float t1v[4], t2v[4]; int t1i[4], t2i[4];
#pragma unroll
        for (int i = 0; i < 4; i++) { t1v[i] = NEGV; t2v[i] = NEGV; t1i[i] = 0x7fffffff; t2i[i] = 0x7fffffff; }
        __syncthreads();   // chunk 0 resident
        for (int ci = 0; ci < nch; ci++) {
            int cb = ub0 + ci * 32;
            if (ci + 1 < nch) stage32(Bsh[(ci + 1) & 1], HsP, cb + 32, wave, lane);   // async prefetch
            const unsigned short* bbase = Bsh[ci & 1];
            int cend = cb + 32; if (cend > uend) cend = uend;
            for (int u0 = cb; u0 < cend; u0 += 16) {
                if (u0 >= wmax) break;   // wave-uniform skip: fully masked for these rows
                int u = u0 + l;
                const unsigned short* bp = &bbase[(u0 - cb + l) * 392 + quad * 8];
                f32x4 acc0 = {0.f, 0.f, 0.f, 0.f};
#pragma unroll
                for (int c = 0; c < 4; c++) {
                    bf16x8 bh = *(const bf16x8*)&bp[c * 96];
                    bf16x8 bm = *(const bf16x8*)&bp[c * 96 + 32];
                    bf16x8 bl = *(const bf16x8*)&bp[c * 96 + 64];
                    acc0 = __builtin_amdgcn_mfma_f32_16x16x32_bf16(afr[c][0], bh, acc0, 0, 0, 0);
                    acc0 = __builtin_amdgcn_mfma_f32_16x16x32_bf16(afr[c][0], bm, acc0, 0, 0, 0);
                    acc0 = __builtin_amdgcn_mfma_f32_16x16x32_bf16(afr[c][1], bh, acc0, 0, 0, 0);
                    acc0 = __builtin_amdgcn_mfma_f32_16x16x32_bf16(afr[c][0], bl, acc0, 0, 0, 0);
                    acc0 = __builtin_amdgcn_mfma_f32_16x16x32_bf16(afr[c][2], bh, acc0, 0, 0, 0);
                    acc0 = __builtin_amdgcn_mfma_f32_16x16x32_bf16(afr[c][1], bm, acc0, 0, 0, 0);
                }
#pragma unroll
                for (int i = 0; i < 4; i++) {
                    float sv = acc0[i];
                    bool gt1 = (u < creg[i]) & (sv > t1v[i]);
                    bool gt2 = (u < creg[i]) & (sv > t2v[i]);
                    float n2v = gt1 ? t1v[i] : (gt2 ? sv : t2v[i]);
                    int   n2i = gt1 ? t1i[i] : (gt2 ? u  : t2i[i]);
                    t1v[i] = gt1 ? sv : t1v[i];
                    t1i[i] = gt1 ? u  : t1i[i];
                    t2v[i] = n2v; t2i[i] = n2i;
                }
            }
            __syncthreads();   // drains prefetch DMA + all waves done reading Bsh[ci&1]
        }
#pragma unroll
        for (int m = 1; m <= 8; m <<= 1) {
#pragma unroll
            for (int i = 0; i < 4; i++) {
                float ov1 = __shfl_xor(t1v[i], m, 64);
                int   oi1 = __shfl_xor(t1i[i], m, 64);
                float ov2 = __shfl_xor(t2v[i], m, 64);
                int   oi2 = __shfl_xor(t2i[i], m, 64);
                bool b1 = (ov1 > t1v[i]) || (ov1 == t1v[i] && oi1 < t1i[i]);
                float w1v = b1 ? ov1 : t1v[i]; int w1i = b1 ? oi1 : t1i[i];
                float l1v = b1 ? t1v[i] : ov1; int l1i = b1 ? t1i[i] : oi1;
                float c2v = b1 ? ov2 : t2v[i]; int c2i = b1 ? oi2 : t2i[i];
                bool b2 = (l1v > c2v) || (l1v == c2v && l1i < c2i);
                t1v[i] = w1v; t1i[i] = w1i;
                t2v[i] = b2 ? l1v : c2v; t2i[i] = b2 ? l1i : c2i;
            }
        }
        if (l == 0) {
#pragma unroll
            for (int i = 0; i < 4; i++) {
                int v = vbase + quad * 4 + i;
                int o = (v * NSEG + seg) * 2;
                pval[o] = t1v[i];     pidx[o] = t1i[i];
                pval[o + 1] = t2v[i]; pidx[o + 1] = t2i[i];
            }
        }
        // no top-of-loop barrier: this tile's final chunk barrier already ordered all
        // tsh reads and Bsh reads before the next tile's tsh write / chunk-0 DMA.
    }
}

// ---------------- fused merge + inversion epilogue: one wave per v (thin, P/Q-reading) ----------------

__global__ __launch_bounds__(256) void k_merge_inv(const float* __restrict__ pval, const int* __restrict__ pidx,
                                                   const int* __restrict__ nact,
                                                   const float* __restrict__ P, const float* __restrict__ Q,
                                                   const float* __restrict__ cz, const float* __restrict__ w2,
                                                   const float* __restrict__ b2, float* __restrict__ out) {
    int gid = blockIdx.x * 256 + threadIdx.x;
    int v = gid >> 6, lane = gid & 63;
    if (v >= NN) return;
    int na = nact[v >> 7];
    float v1 = NEGV, v2 = NEGV; int i1 = 0x7fffffff, i2 = 0x7fffffff;
    if (lane < na) {
        int o = (v * NSEG + lane) * 2;
        v1 = pval[o];     i1 = pidx[o];
        v2 = pval[o + 1]; i2 = pidx[o + 1];
    }
#pragma unroll
    for (int m = 1; m <= 32; m <<= 1) {
        float ov1 = __shfl_xor(v1, m, 64);
        int   oi1 = __shfl_xor(i1, m, 64);
        float ov2 = __shfl_xor(v2, m, 64);
        int   oi2 = __shfl_xor(i2, m, 64);
        bool b1 = (ov1 > v1) || (ov1 == v1 && oi1 < i1);
        float w1v = b1 ? ov1 : v1; int w1i = b1 ? oi1 : i1;
        float l1v = b1 ? v1 : ov1; int l1i = b1 ? i1 : oi1;
        float c2v = b1 ? ov2 : v2; int c2i = b1 ? oi2 : i2;
        bool b2 = (l1v > c2v) || (l1v == c2v && l1i < c2i);
        v1 = w1v; i1 = w1i;
        v2 = b2 ? l1v : c2v; i2 = b2 ? l1i : c2i;
    }
    // resolve NEGV sentinels (matches reference top_k over all-NEG candidates: lowest indices)
    if (v1 == NEGV) { v2 = NEGV; i1 = 0; i2 = 1; }
    else if (v2 == NEGV) { i2 = (i1 == 0) ? 1 : 0; }
    int u1 = i1, u2 = i2;   // now always in [0, NN)
    float cza = cz[lane], czb = cz[64 + lane];
    float w2a = w2[lane], w2b = w2[64 + lane];
    float Qa = Q[(size_t)v * HH + lane], Qb = Q[(size_t)v * HH + 64 + lane];
    float p0 = fmaxf(P[(size_t)u1 * HH + lane] + Qa + cza, 0.f) * w2a +
               fmaxf(P[(size_t)u1 * HH + 64 + lane] + Qb + czb, 0.f) * w2b;
    float p1 = fmaxf(P[(size_t)u2 * HH + lane] + Qa + cza, 0.f) * w2a +
               fmaxf(P[(size_t)u2 * HH + 64 + lane] + Qb + czb, 0.f) * w2b;
#pragma unroll
    for (int off = 32; off >= 1; off >>= 1) {
        p0 += __shfl_down(p0, off, 64);
        p1 += __shfl_down(p1, off, 64);
    }
    if (lane == 0) {
        float bb = b2[0];
        float l0 = p0 + bb, l1 = p1 + bb;
        out[v * 2 + 0] = v1; out[v * 2 + 1] = v2;                 // top_vals
        out[NN * 2 + v * 2 + 0] = l0;                             // inv_logit
        out[NN * 2 + v * 2 + 1] = l1;
        out[2 * NN * 2 + v * 2 + 0] = (float)i1;                  // top_idx
        out[2 * NN * 2 + v * 2 + 1] = (float)i2;
        out[3 * NN * 2 + v * 2 + 0] = (l0 > 0.f) ? 1.f : 0.f;     // inv_bit
        out[3 * NN * 2 + v * 2 + 1] = (l1 > 0.f) ? 1.f : 0.f;
    }
}

// ---------------- launch ----------------

extern "C" void kernel_launch(void* const* d_in, const int* in_sizes, int n_in,
                              void* d_out, int out_size, void* d_ws, size_t ws_size,
                              hipStream_t stream) {
    const float* x       = (const float*)d_in[0];
    const float* z       = (const float*)d_in[1];
    const int*   eidx    = (const int*)d_in[2];
    const int*   depth   = (const int*)d_in[3];
    const float* conv1_w = (const float*)d_in[4];
    const float* conv1_b = (const float*)d_in[5];
    const float* conv2_w = (const float*)d_in[6];
    const float* conv2_b = (const float*)d_in[7];
    const float* np1_w   = (const float*)d_in[8];
    const float* np1_b   = (const float*)d_in[9];
    const float* np2_w   = (const float*)d_in[10];
    const float* np2_b   = (const float*)d_in[11];
    const float* src_w   = (const float*)d_in[12];
    const float* tgt_w   = (const float*)d_in[13];
    const float* inv1_w  = (const float*)d_in[14];
    const float* inv1_b  = (const float*)d_in[15];
    const float* inv2_w  = (const float*)d_in[16];
    const float* inv2_b  = (const float*)d_in[17];
    float* out = (float*)d_out;
    float* wsf = (float*)d_ws;

    const int NH = NN * HH;   // 1,048,576 floats = 4 MB
    float* R0 = wsf;                          // h2/h3
    float* R1 = wsf + (size_t)NH;             // xw2 / planes / (P,Q after stage1)
    unsigned short* HtP = (unsigned short*)R1;
    unsigned short* HsP = HtP + 3 * (size_t)NH;
    float* P = wsf + (size_t)NH;              // aliases planes — written AFTER stage1
    float* Q = wsf + 2 * (size_t)NH;
    float* pval = wsf + 4 * (size_t)NH;
    int*   pidx = (int*)(wsf + 5 * (size_t)NH);
    float* T  = wsf + 6 * (size_t)NH;
    float* c1 = T + 7 * 16384;
    float* cz = c1 + 128;
    float* rsq  = cz + 128;
    float* dinv = rsq + NN;
    int* degi   = (int*)(dinv + NN);
    int* rowptr = degi + NN;             // NN+1
    int* cursor = rowptr + NN + 1;
    int* cnt    = cursor + NN;
    int* nact   = cnt + NN;              // 64
    int* ntiles = nact + 64;
    int* tctr   = ntiles + 1;
    int* tlist  = tctr + 1;              // <= 4096
    int* ecsr   = tlist + 4096;          // EE

    const int* esrc = eidx;
    const int* edst = eidx + EE;

    hipMemsetAsync(degi, 0, NN * sizeof(int), stream);
    k_init<<<1057, 256, 0, stream>>>(edst, degi, conv2_w, np1_w, np2_w, src_w, tgt_w, inv1_w,
                                     np1_b, inv1_b, z, T, c1, cz, depth, x, cnt, out, cursor, tctr);
    k_scan_tiles<<<2, 1024, 0, stream>>>(degi, rowptr, dinv, rsq, cnt, nact, tlist, ntiles);
    k_fill<<<EE / 256, 256, 0, stream>>>(esrc, edst, rowptr, cursor, ecsr);
    k_gather1xw<<<NN * 64 / 256, 256, 0, stream>>>(rowptr, ecsr, rsq, dinv, x, conv1_w, conv1_b,
                                                   T + 0 * 16384, R1);                 // xw2
    k_gather2<<<NN * 64 / 256, 256, 0, stream>>>(rowptr, ecsr, rsq, dinv, R1, conv2_b, R0);   // h2
    k_mlp<<<512, 256, 0, stream>>>(R0, T, c1, np2_b, R0, HtP, HsP);        // h3 (in-place) + planes
    k_top2_stage1<<<768, 512, 0, stream>>>(HtP, HsP, cnt, tlist, ntiles, tctr, pval, pidx);
    k_gemmPQ<<<512, 256, 0, stream>>>(R0, T + 5 * 16384, T + 6 * 16384, P, Q);   // P,Q = h3@inv1{a,b}^T
    k_merge_inv<<<NN / 4, 256, 0, stream>>>(pval, pidx, nact, P, Q, cz, inv2_w, inv2_b, out);
}